// Round 7
// baseline (102.236 us; speedup 1.0000x reference)
//
#include <hip/hip_runtime.h>
#include <math.h>

// The reference network is ENTIRELY LINEAR before log_softmax, so it
// collapses to logits[b,n] = b_cls[n] + <x[b], Wx[n]>, Wx: (10,3,32,32),
// where Wx is the classifier pushed backward through both decomposed convs
// (composes into ONE 5x5 full-correlation applied to Wcls):
//   M[r1,r2]    = sum_f l1_f0[f,r1]*l2_f3[f,r2]
//   K[c,ij,r2]  = sum_r1 l1_f3[c,r1]*(l1_f1[i,r1]*l1_f2[j,r1])*M[r1,r2]
//   E[c,r2,u,v] = sum_{i+k=u, j+l=v} K[c,ij,r2]*(l2_f1[k,r2]*l2_f2[l,r2])
//   G[c,uv,f]   = sum_r2 E[c,r2,uv]*l2_f0[f,r2]            (3x25x32)
//   Wx[n,c,H,W] = sum_{uv: 0<=H-u<28, 0<=W-v<28} sum_f
//                     G[c,uv,f] * Wcls[n, f*784+(H-u)*28+(W-v)]
//
// Round-7: cooperative launch killed the container (round 6) -> back to two
// REGULAR dispatches, but with the parallelized Wx build:
//   wx_kernel: 480 blocks (was 120) x 256 thr; G built redundantly per
//     block (tiny); 4 threads per Wx element split the f-sum (8 f each),
//     quad shfl_xor reduce. 1920 waves -> latency-hiding across CUs.
//   cls_kernel: unchanged (proven): 1 block/image, float4 dot + log_softmax.

// ---- K1: Wx (480 blocks x 256 thr; 4 threads per element) ----
__global__ __launch_bounds__(256) void wx_kernel(
    const float* __restrict__ l1_f0, const float* __restrict__ l1_f1,
    const float* __restrict__ l1_f2, const float* __restrict__ l1_f3,
    const float* __restrict__ l2_f0, const float* __restrict__ l2_f1,
    const float* __restrict__ l2_f2, const float* __restrict__ l2_f3,
    const float* __restrict__ Wcls,
    float* __restrict__ Wx) {
    __shared__ float sM[256];        // [r1][r2]
    __shared__ float sK[432];        // [(c*9+ij)*16 + r2]
    __shared__ float sE[1200];       // [(c*25+uv)*16 + r2]
    __shared__ float sG[2400];       // [(c*25+uv)*32 + f]
    const int tid = threadIdx.x;

    // phase 1: M
    {
        int r1 = tid >> 4, r2 = tid & 15;
        float acc = 0.f;
#pragma unroll
        for (int f = 0; f < 32; ++f)
            acc += l1_f0[f * 16 + r1] * l2_f3[f * 16 + r2];
        sM[tid] = acc;
    }
    __syncthreads();
    // phase 2: K
    for (int t = tid; t < 432; t += 256) {
        int r2 = t & 15;
        int e = t >> 4;              // c*9 + ij
        int c = e / 9, ij = e - c * 9;
        int i = ij / 3, j = ij - i * 3;
        float acc = 0.f;
#pragma unroll
        for (int r1 = 0; r1 < 16; ++r1)
            acc += l1_f3[c * 16 + r1] * l1_f1[i * 16 + r1] * l1_f2[j * 16 + r1]
                 * sM[r1 * 16 + r2];
        sK[t] = acc;
    }
    __syncthreads();
    // phase 3: E (5x5 composition)
    for (int t = tid; t < 1200; t += 256) {
        int r2 = t & 15;
        int e = t >> 4;              // c*25 + uv
        int c = e / 25, uv = e - c * 25;
        int u = uv / 5, v = uv - u * 5;
        float acc = 0.f;
        int ilo = u > 2 ? u - 2 : 0, ihi = u < 2 ? u : 2;
        int jlo = v > 2 ? v - 2 : 0, jhi = v < 2 ? v : 2;
        for (int i = ilo; i <= ihi; ++i) {
            int k = u - i;
            for (int j = jlo; j <= jhi; ++j) {
                int l = v - j;
                acc += sK[(c * 9 + i * 3 + j) * 16 + r2]
                     * l2_f1[k * 16 + r2] * l2_f2[l * 16 + r2];
            }
        }
        sE[t] = acc;
    }
    __syncthreads();
    // phase 4: G
    for (int t = tid; t < 2400; t += 256) {
        int f = t & 31;
        int e = t >> 5;              // c*25 + uv
        float acc = 0.f;
#pragma unroll
        for (int r2 = 0; r2 < 16; ++r2)
            acc += sE[e * 16 + r2] * l2_f0[f * 16 + r2];
        sG[t] = acc;
    }
    __syncthreads();

    // phase 5: 4 threads per Wx element (f-sum split 8 each)
    const int t = blockIdx.x * 64 + (tid >> 2);   // element, 0..30719
    const int fg = (tid & 3) * 8;                 // this thread's f-range
    const int n = t / 3072;
    const int rem = t - n * 3072;
    const int c = rem >> 10;
    const int p = rem & 1023;
    const int H = p >> 5, W = p & 31;
    const float* wn = Wcls + n * 25088 + fg * 784;
    float acc = 0.f;
#pragma unroll
    for (int u = 0; u < 5; ++u) {
        int hh = H - u;
        if (hh < 0 || hh >= 28) continue;
#pragma unroll
        for (int v = 0; v < 5; ++v) {
            int ww = W - v;
            if (ww < 0 || ww >= 28) continue;
            const float* wp = wn + hh * 28 + ww;
            const float* gp = &sG[(c * 25 + u * 5 + v) * 32 + fg];
#pragma unroll
            for (int f = 0; f < 8; ++f)
                acc += gp[f] * wp[f * 784];
        }
    }
    acc += __shfl_xor(acc, 1, 64);
    acc += __shfl_xor(acc, 2, 64);
    if ((tid & 3) == 0) Wx[t] = acc;   // layout n*3072+c*1024+H*32+W (matches x)
}

// ---- K2: logits = x . Wx^T + b, then log_softmax. One block per image ----
__global__ __launch_bounds__(256) void cls_kernel(
    const float* __restrict__ x, const float* __restrict__ Wx,
    const float* __restrict__ b_cls, float* __restrict__ out) {
    __shared__ float sred[4][10];
    __shared__ float slog[10];
    const int tid = threadIdx.x;
    const int b = blockIdx.x;
    const float4* xb = (const float4*)(x + b * 3072);
    const float4* wx4 = (const float4*)Wx;

    float acc[10];
#pragma unroll
    for (int n = 0; n < 10; ++n) acc[n] = 0.f;
#pragma unroll
    for (int k = 0; k < 3; ++k) {
        const int idx = tid + k * 256;      // 0..767 float4 chunks
        float4 xv = xb[idx];
#pragma unroll
        for (int n = 0; n < 10; ++n) {
            float4 wv = wx4[n * 768 + idx];
            acc[n] += xv.x * wv.x + xv.y * wv.y + xv.z * wv.z + xv.w * wv.w;
        }
    }

    const int lane = tid & 63, wid = tid >> 6;
#pragma unroll
    for (int n = 0; n < 10; ++n) {
        float v = acc[n];
        for (int off = 32; off > 0; off >>= 1)
            v += __shfl_down(v, off, 64);
        if (lane == 0) sred[wid][n] = v;
    }
    __syncthreads();
    if (tid < 10) {
        slog[tid] = b_cls[tid] + sred[0][tid] + sred[1][tid]
                  + sred[2][tid] + sred[3][tid];
    }
    __syncthreads();
    if (tid < 10) {
        float m = -1e30f;
#pragma unroll
        for (int n = 0; n < 10; ++n) m = fmaxf(m, slog[n]);
        float ssum = 0.f;
#pragma unroll
        for (int n = 0; n < 10; ++n) ssum += expf(slog[n] - m);
        out[b * 10 + tid] = slog[tid] - m - logf(ssum);
    }
}

extern "C" void kernel_launch(void* const* d_in, const int* in_sizes, int n_in,
                              void* d_out, int out_size, void* d_ws, size_t ws_size,
                              hipStream_t stream) {
    const float* x     = (const float*)d_in[0];
    const float* l1_f0 = (const float*)d_in[1];
    const float* l1_f1 = (const float*)d_in[2];
    const float* l1_f2 = (const float*)d_in[3];
    const float* l1_f3 = (const float*)d_in[4];
    const float* l2_f0 = (const float*)d_in[5];
    const float* l2_f1 = (const float*)d_in[6];
    const float* l2_f2 = (const float*)d_in[7];
    const float* l2_f3 = (const float*)d_in[8];
    const float* Wcls  = (const float*)d_in[9];
    const float* bcls  = (const float*)d_in[10];
    float* out = (float*)d_out;

    float* Wx = (float*)d_ws;          // 30720 floats (120 KB)

    wx_kernel<<<dim3(480), dim3(256), 0, stream>>>(
        l1_f0, l1_f1, l1_f2, l1_f3, l2_f0, l2_f1, l2_f2, l2_f3, Wcls, Wx);
    cls_kernel<<<dim3(512), dim3(256), 0, stream>>>(x, Wx, bcls, out);
}

// Round 8
// 92.716 us; speedup vs baseline: 1.1027x; 1.1027x over previous
//
#include <hip/hip_runtime.h>
#include <math.h>

// The reference network is ENTIRELY LINEAR before log_softmax, so it
// collapses to logits[b,n] = b_cls[n] + <x[b], Wx[n]>, Wx: (10,3,32,32).
// Fold chain (verified absmax 0.0, rounds 4/5/7):
//   M[r1,r2]    = sum_f l1_f0[f,r1]*l2_f3[f,r2]
//   K[c,ij,r2]  = sum_r1 l1_f3[c,r1]*(l1_f1[i,r1]*l1_f2[j,r1])*M[r1,r2]
//   Wc2[n,r2,q784]  = sum_f l2_f0[f,r2]*W_cls[n,f*784+q]
//   Wc3[n,r2,h,w30] = sum_{ij valid<28} cw2[r2,ij]*Wc2[n,r2,h-i,w-j]
//   Wx[n,c,H,W32]   = sum_{ij valid<30} sum_r2 K[c,ij,r2]*Wc3[n,r2,H-i,W-j]
//
// Round-8: round-4's 3-dispatch structure (best measured, 93.0us; its
// precomp1 sweeps Wcls q-major fully coalesced, unlike the merged round-5/7
// wx_kernel's scattered stride-784 taps) with ONE change: precomp2
// parallelized 4x (480 blocks, 4 threads/element splitting the r2-sum,
// quad shfl_xor reduce - pattern validated in round 7 phase 5).
// Cost model: ~80us fixed harness poison fills + ~13us ours.

// ---- P1: Wc3 (blocks 0..159 = (n,r2)), M + K (block 160) ----
__global__ __launch_bounds__(256) void precomp1(
    const float* __restrict__ l1_f0, const float* __restrict__ l1_f1,
    const float* __restrict__ l1_f2, const float* __restrict__ l1_f3,
    const float* __restrict__ l2_f0, const float* __restrict__ l2_f1,
    const float* __restrict__ l2_f2, const float* __restrict__ l2_f3,
    const float* __restrict__ Wcls,
    float* __restrict__ Wc3, float* __restrict__ Kc) {
    __shared__ float sWc2[784];
    __shared__ float sM[256];
    const int tid = threadIdx.x;
    const int blk = blockIdx.x;

    if (blk < 160) {
        const int n = blk >> 4, r2 = blk & 15;
        // Wc2[n,r2,:] -> LDS (q-major, coalesced Wcls sweep)
        for (int q = tid; q < 784; q += 256) {
            float acc = 0.f;
#pragma unroll
            for (int f = 0; f < 32; ++f)
                acc += l2_f0[f * 16 + r2] * Wcls[n * 25088 + f * 784 + q];
            sWc2[q] = acc;
        }
        __syncthreads();
        float cw[9];
#pragma unroll
        for (int ij = 0; ij < 9; ++ij) {
            int i = ij / 3, j = ij - (ij / 3) * 3;
            cw[ij] = l2_f1[i * 16 + r2] * l2_f2[j * 16 + r2];
        }
        // full-correlation: Wc3[h,w] = sum_{ij valid} cw[ij]*Wc2[h-i,w-j]
        for (int p = tid; p < 900; p += 256) {
            int h = p / 30, w = p - (p / 30) * 30;
            float acc = 0.f;
#pragma unroll
            for (int i = 0; i < 3; ++i) {
                int hh = h - i;
                if (hh < 0 || hh > 27) continue;
#pragma unroll
                for (int j = 0; j < 3; ++j) {
                    int ww = w - j;
                    if (ww < 0 || ww > 27) continue;
                    acc += cw[i * 3 + j] * sWc2[hh * 28 + ww];
                }
            }
            Wc3[blk * 900 + p] = acc;
        }
    } else {
        // M[r1,r2] then K[c,ij,r2]
        {
            int r1 = tid >> 4, r2 = tid & 15;
            float acc = 0.f;
#pragma unroll
            for (int f = 0; f < 32; ++f)
                acc += l1_f0[f * 16 + r1] * l2_f3[f * 16 + r2];
            sM[tid] = acc;
        }
        __syncthreads();
        for (int t = tid; t < 432; t += 256) {
            int c = t / 144;
            int rem = t - c * 144;
            int ij = rem >> 4;
            int r2 = rem & 15;
            int i = ij / 3, j = ij - i * 3;
            float acc = 0.f;
#pragma unroll
            for (int r1 = 0; r1 < 16; ++r1) {
                float cw1v = l1_f1[i * 16 + r1] * l1_f2[j * 16 + r1];
                acc += l1_f3[c * 16 + r1] * cw1v * sM[r1 * 16 + r2];
            }
            Kc[t] = acc;   // layout (c*9+ij)*16 + r2
        }
    }
}

// ---- P2: Wx[n,c,H,W] from Wc3 and K; 4 threads/element (r2-sum split) ----
__global__ __launch_bounds__(256) void precomp2(
    const float* __restrict__ Wc3, const float* __restrict__ Kc,
    float* __restrict__ Wx) {
    const int t = blockIdx.x * 64 + (threadIdx.x >> 2);   // element 0..30719
    const int rq = (threadIdx.x & 3) * 4;                 // r2-range base
    const int n = t / 3072;
    const int rem = t - n * 3072;
    const int c = rem >> 10;
    const int p = rem & 1023;
    const int H = p >> 5, W = p & 31;
    const float* wn = Wc3 + n * 14400 + rq * 900;
    float acc = 0.f;
#pragma unroll
    for (int i = 0; i < 3; ++i) {
        int hh = H - i;
        if (hh < 0 || hh >= 30) continue;
#pragma unroll
        for (int j = 0; j < 3; ++j) {
            int ww = W - j;
            if (ww < 0 || ww >= 30) continue;
            const float* wp = wn + hh * 30 + ww;
            const float* kp = Kc + (c * 9 + i * 3 + j) * 16 + rq;
#pragma unroll
            for (int r2 = 0; r2 < 4; ++r2)
                acc += kp[r2] * wp[r2 * 900];
        }
    }
    acc += __shfl_xor(acc, 1, 64);
    acc += __shfl_xor(acc, 2, 64);
    if ((threadIdx.x & 3) == 0)
        Wx[t] = acc;   // t = n*3072 + c*1024 + p  (matches x's (c,H,W) layout)
}

// ---- P3: logits = x . Wx^T + b, then log_softmax. One block per image ----
__global__ __launch_bounds__(256) void cls_kernel(
    const float* __restrict__ x, const float* __restrict__ Wx,
    const float* __restrict__ b_cls, float* __restrict__ out) {
    __shared__ float sred[4][10];
    __shared__ float slog[10];
    const int tid = threadIdx.x;
    const int b = blockIdx.x;
    const float4* xb = (const float4*)(x + b * 3072);
    const float4* wx4 = (const float4*)Wx;

    float acc[10];
#pragma unroll
    for (int n = 0; n < 10; ++n) acc[n] = 0.f;
#pragma unroll
    for (int k = 0; k < 3; ++k) {
        const int idx = tid + k * 256;      // 0..767 float4 chunks
        float4 xv = xb[idx];
#pragma unroll
        for (int n = 0; n < 10; ++n) {
            float4 wv = wx4[n * 768 + idx];
            acc[n] += xv.x * wv.x + xv.y * wv.y + xv.z * wv.z + xv.w * wv.w;
        }
    }

    const int lane = tid & 63, wid = tid >> 6;
#pragma unroll
    for (int n = 0; n < 10; ++n) {
        float v = acc[n];
        for (int off = 32; off > 0; off >>= 1)
            v += __shfl_down(v, off, 64);
        if (lane == 0) sred[wid][n] = v;
    }
    __syncthreads();
    if (tid < 10) {
        slog[tid] = b_cls[tid] + sred[0][tid] + sred[1][tid]
                  + sred[2][tid] + sred[3][tid];
    }
    __syncthreads();
    if (tid < 10) {
        float m = -1e30f;
#pragma unroll
        for (int n = 0; n < 10; ++n) m = fmaxf(m, slog[n]);
        float ssum = 0.f;
#pragma unroll
        for (int n = 0; n < 10; ++n) ssum += expf(slog[n] - m);
        out[b * 10 + tid] = slog[tid] - m - logf(ssum);
    }
}

extern "C" void kernel_launch(void* const* d_in, const int* in_sizes, int n_in,
                              void* d_out, int out_size, void* d_ws, size_t ws_size,
                              hipStream_t stream) {
    const float* x     = (const float*)d_in[0];
    const float* l1_f0 = (const float*)d_in[1];
    const float* l1_f1 = (const float*)d_in[2];
    const float* l1_f2 = (const float*)d_in[3];
    const float* l1_f3 = (const float*)d_in[4];
    const float* l2_f0 = (const float*)d_in[5];
    const float* l2_f1 = (const float*)d_in[6];
    const float* l2_f2 = (const float*)d_in[7];
    const float* l2_f3 = (const float*)d_in[8];
    const float* Wcls  = (const float*)d_in[9];
    const float* bcls  = (const float*)d_in[10];
    float* out = (float*)d_out;

    float* Wc3 = (float*)d_ws;          // 10*16*900 = 144000 floats (576 KB)
    float* Kc  = Wc3 + 144000;          // 432 floats
    float* Wx  = Kc + 432;              // 10*3*1024 = 30720 floats (120 KB)

    precomp1<<<dim3(161), dim3(256), 0, stream>>>(
        l1_f0, l1_f1, l1_f2, l1_f3, l2_f0, l2_f1, l2_f2, l2_f3, Wcls, Wc3, Kc);
    precomp2<<<dim3(480), dim3(256), 0, stream>>>(Wc3, Kc, Wx);
    cls_kernel<<<dim3(512), dim3(256), 0, stream>>>(x, Wx, bcls, out);
}